// Round 6
// baseline (148.753 us; speedup 1.0000x reference)
//
#include <hip/hip_runtime.h>
#include <stdint.h>

#define LEN 512
#define NB 64
#define NCX 64
#define NCV 4
#define NCU 4

typedef float f4 __attribute__((ext_vector_type(4)));

// ---------------- Threefry-2x32, 20 rounds, key = (0, 42) ----------------
__device__ __forceinline__ uint32_t rotl32(uint32_t v, int r) {
  return (v << r) | (v >> (32 - r));
}

__device__ __forceinline__ void threefry2x32_k042(uint32_t c0, uint32_t c1,
                                                  uint32_t& o0, uint32_t& o1) {
  const uint32_t ks0 = 0u, ks1 = 42u;
  const uint32_t ks2 = 0u ^ 42u ^ 0x1BD11BDAu;
  uint32_t x0 = c0 + ks0;
  uint32_t x1 = c1 + ks1;
#define TF_ROUND(R) { x0 += x1; x1 = rotl32(x1, R); x1 ^= x0; }
  TF_ROUND(13) TF_ROUND(15) TF_ROUND(26) TF_ROUND(6)
  x0 += ks1; x1 += ks2 + 1u;
  TF_ROUND(17) TF_ROUND(29) TF_ROUND(16) TF_ROUND(24)
  x0 += ks2; x1 += ks0 + 2u;
  TF_ROUND(13) TF_ROUND(15) TF_ROUND(26) TF_ROUND(6)
  x0 += ks0; x1 += ks1 + 3u;
  TF_ROUND(17) TF_ROUND(29) TF_ROUND(16) TF_ROUND(24)
  x0 += ks1; x1 += ks2 + 4u;
  TF_ROUND(13) TF_ROUND(15) TF_ROUND(26) TF_ROUND(6)
  x0 += ks2; x1 += ks0 + 5u;
#undef TF_ROUND
  o0 = x0; o1 = x1;
}

// ---------------- Kernel 1: permutation (fwd + inverse), ml, mask_p -------
// perm semantics (matches jnp.argsort(-rand) stable ascending):
//   positions [0, n_inv): invalid slots ordered by rand DESC, ties idx ASC
//   positions [n_inv, L): valid slots in original index order
__global__ __launch_bounds__(LEN) void build_perm(const void* __restrict__ mask,
                                                  int* __restrict__ src,
                                                  int* __restrict__ dst,
                                                  int* __restrict__ ml_arr,
                                                  float* __restrict__ mask_out) {
  const int b = blockIdx.x;
  const int l = threadIdx.x;
  const int wave = l >> 6, lane = l & 63;
  __shared__ uint32_t inv_key[LEN];
  __shared__ int inv_idx[LEN];
  __shared__ int wsum[8];
  __shared__ int woff[9];

  // runtime mask-dtype detection: first element is always valid (len >= 256)
  const uint32_t w0 = ((const uint32_t*)mask)[0];
  bool valid;
  if (w0 == 1u) {                       // int32 0/1
    valid = ((const int*)mask)[b * LEN + l] != 0;
  } else if (w0 == 0x3F800000u) {       // float32 0.0/1.0
    valid = ((const float*)mask)[b * LEN + l] != 0.0f;
  } else {                              // 1-byte bool
    valid = ((const unsigned char*)mask)[b * LEN + l] != 0;
  }
  const bool inv = !valid;

  uint32_t o0, o1;
  threefry2x32_k042(0u, (uint32_t)(b * LEN + l), o0, o1);
  const uint32_t bits = o0 ^ o1;
  const uint32_t ui = (bits >> 9) | 0x3F800000u;  // monotone in uniform value

  // order-preserving compaction of invalid slots
  const unsigned long long bal = __ballot(inv);
  const int lower = __popcll(bal & ((1ull << lane) - 1ull));
  if (lane == 0) wsum[wave] = __popcll(bal);
  __syncthreads();
  if (l == 0) {
    int acc = 0;
    for (int w = 0; w < 8; ++w) { woff[w] = acc; acc += wsum[w]; }
    woff[8] = acc;
  }
  __syncthreads();
  const int n_inv = woff[8];
  const int inv_before = woff[wave] + lower;  // # invalid with index < l
  if (inv) {
    inv_key[inv_before] = ui;
    inv_idx[inv_before] = l;
  }
  __syncthreads();

  int pos;
  if (inv) {
    int rank = 0;
    for (int j = 0; j < n_inv; ++j) {
      const uint32_t kj = inv_key[j];
      rank += (kj > ui || (kj == ui && inv_idx[j] < l)) ? 1 : 0;
    }
    pos = rank;
  } else {
    pos = n_inv + (l - inv_before);  // valid slots keep original order
  }
  src[b * LEN + pos] = l;
  dst[b * LEN + l] = pos;            // inverse permutation

  const int nv = LEN - n_inv;
  const int ml = nv < 1 ? 1 : nv;
  if (l == 0) ml_arr[b] = ml;
  mask_out[b * LEN + l] = (l >= n_inv && l < ml) ? 1.0f : 0.0f;
}

// ---------------- Kernel 2: uu + fused x/v gather ----------------
// out[b,c,dst[i'],j] = in[b,c,i',src[j]]: sequential reads, column gather in
// wave-private LDS, full-row writes at permuted offsets.
// XCD-aware swizzle: all 16 blocks of one (b,c) plane land on the SAME XCD
// (xcd = blk%8, each XCD owns 32 contiguous planes), so the 2KB-granular
// scattered row writes aggregate in that XCD's 4MB L2 and evict as dense
// plane-local bursts instead of random 2KB DRAM writes.
__global__ __launch_bounds__(256) void uu_perm(const float* __restrict__ in,
                                               float* __restrict__ out,
                                               const float* __restrict__ xin,
                                               const float* __restrict__ vin,
                                               float* __restrict__ xout,
                                               float* __restrict__ vout,
                                               const int* __restrict__ src,
                                               const int* __restrict__ dst,
                                               const int* __restrict__ ml_arr) {
  __shared__ float s_row[4][LEN];
  const int tid = threadIdx.x;
  const int wave = tid >> 6, lane = tid & 63;

  // ---- XCD-aware plane grouping (bijective: 4096 % 8 == 0) ----
  const int blk = blockIdx.x;
  const int xcd = blk & 7;                   // dispatch round-robin -> XCD id
  const int j = blk >> 3;                    // [0, 512) within XCD
  const int plane_id = xcd * 32 + (j >> 4);  // [0, 256): all 16 chunks same XCD
  const int chunk = j & 15;
  const int b = plane_id >> 2;               // plane = b*4 + c
  const int i0 = chunk * 32 + wave * 8;      // input row within plane
  const long plane = (long)plane_id * LEN * LEN;
  const float* ip = in + plane + (long)i0 * LEN + lane * 8;

  // ---- issue all 16 sequential row loads first ----
  f4 a0[8], a1[8];
#pragma unroll
  for (int r = 0; r < 8; ++r) {
    a0[r] = *(const f4*)(ip + (long)r * LEN);
    a1[r] = *(const f4*)(ip + (long)r * LEN + 4);
  }

  // column gather sources (same for all rows) and destination rows
  int c[8];
#pragma unroll
  for (int kk = 0; kk < 8; ++kk) c[kk] = src[b * LEN + lane * 8 + kk];
  int dr[8];
#pragma unroll
  for (int r = 0; r < 8; ++r) dr[r] = dst[b * LEN + i0 + r];

  float* myrow = &s_row[wave][0];

#pragma unroll
  for (int r = 0; r < 8; ++r) {
    *(f4*)(myrow + lane * 8) = a0[r];
    *(f4*)(myrow + lane * 8 + 4) = a1[r];
    f4 q0, q1;
    q0.x = myrow[c[0]]; q0.y = myrow[c[1]]; q0.z = myrow[c[2]]; q0.w = myrow[c[3]];
    q1.x = myrow[c[4]]; q1.y = myrow[c[5]]; q1.z = myrow[c[6]]; q1.w = myrow[c[7]];
    f4* op = (f4*)(out + plane + (long)dr[r] * LEN + lane * 8);
    op[0] = q0;
    op[1] = q1;
  }

  // ---- fused x/v gather + trim: keyed off RAW blockIdx (still a bijective
  //      cover of (b2, k) pairs) ----
  const int b2 = blk >> 6;
  const int k = blk & 63;
  const int ml = ml_arr[b2];
  const int* srcb = src + b2 * LEN;
  {
    const float* xrow = xin + (long)((b2 << 6) + k) * LEN;
    float* orow = xout + (long)((b2 << 6) + k) * LEN;
    for (int p = tid; p < LEN; p += 256) {
      orow[p] = (p < ml) ? xrow[srcb[p]] : 0.0f;
    }
  }
  if (k < NCV) {
    const float* vrow = vin + (long)((b2 << 2) + k) * LEN;
    float* orow = vout + (long)((b2 << 2) + k) * LEN;
    for (int p = tid; p < LEN; p += 256) {
      orow[p] = (p < ml) ? vrow[srcb[p]] : 0.0f;
    }
  }
}

extern "C" void kernel_launch(void* const* d_in, const int* in_sizes, int n_in,
                              void* d_out, int out_size, void* d_ws, size_t ws_size,
                              hipStream_t stream) {
  const float* x  = (const float*)d_in[0];   // (64,64,512)
  const float* v  = (const float*)d_in[1];   // (64,4,512)
  const float* uu = (const float*)d_in[2];   // (64,4,512,512)
  const void*  mask = d_in[3];               // (64,1,512)

  float* out   = (float*)d_out;
  float* out_x = out;                        // 2,097,152
  float* out_v = out + 2097152;              // 131,072
  float* out_m = out + 2228224;              // 32,768
  float* out_u = out + 2260992;              // 67,108,864

  int* src = (int*)d_ws;                     // 64*512 ints
  int* dst = src + NB * LEN;                 // 64*512 ints
  int* ml  = dst + NB * LEN;                 // 64 ints

  build_perm<<<NB, LEN, 0, stream>>>(mask, src, dst, ml, out_m);

  uu_perm<<<(NB * NCU * LEN) / 32, 256, 0, stream>>>(
      uu, out_u, x, v, out_x, out_v, src, dst, ml);
}

// Round 7
// 135.037 us; speedup vs baseline: 1.1016x; 1.1016x over previous
//
#include <hip/hip_runtime.h>
#include <stdint.h>

#define LEN 512
#define NB 64
#define NCX 64
#define NCV 4
#define NCU 4

typedef float f4 __attribute__((ext_vector_type(4)));

// ---------------- Threefry-2x32, 20 rounds, key = (0, 42) ----------------
__device__ __forceinline__ uint32_t rotl32(uint32_t v, int r) {
  return (v << r) | (v >> (32 - r));
}

__device__ __forceinline__ void threefry2x32_k042(uint32_t c0, uint32_t c1,
                                                  uint32_t& o0, uint32_t& o1) {
  const uint32_t ks0 = 0u, ks1 = 42u;
  const uint32_t ks2 = 0u ^ 42u ^ 0x1BD11BDAu;
  uint32_t x0 = c0 + ks0;
  uint32_t x1 = c1 + ks1;
#define TF_ROUND(R) { x0 += x1; x1 = rotl32(x1, R); x1 ^= x0; }
  TF_ROUND(13) TF_ROUND(15) TF_ROUND(26) TF_ROUND(6)
  x0 += ks1; x1 += ks2 + 1u;
  TF_ROUND(17) TF_ROUND(29) TF_ROUND(16) TF_ROUND(24)
  x0 += ks2; x1 += ks0 + 2u;
  TF_ROUND(13) TF_ROUND(15) TF_ROUND(26) TF_ROUND(6)
  x0 += ks0; x1 += ks1 + 3u;
  TF_ROUND(17) TF_ROUND(29) TF_ROUND(16) TF_ROUND(24)
  x0 += ks1; x1 += ks2 + 4u;
  TF_ROUND(13) TF_ROUND(15) TF_ROUND(26) TF_ROUND(6)
  x0 += ks2; x1 += ks0 + 5u;
#undef TF_ROUND
  o0 = x0; o1 = x1;
}

// ---------------- Kernel 1: permutation (fwd + inverse), ml, mask_p -------
// perm semantics (matches jnp.argsort(-rand) stable ascending):
//   positions [0, n_inv): invalid slots ordered by rand DESC, ties idx ASC
//   positions [n_inv, L): valid slots in original index order
__global__ __launch_bounds__(LEN) void build_perm(const void* __restrict__ mask,
                                                  int* __restrict__ src,
                                                  int* __restrict__ dst,
                                                  int* __restrict__ ml_arr,
                                                  float* __restrict__ mask_out) {
  const int b = blockIdx.x;
  const int l = threadIdx.x;
  const int wave = l >> 6, lane = l & 63;
  __shared__ uint32_t inv_key[LEN];
  __shared__ int inv_idx[LEN];
  __shared__ int wsum[8];
  __shared__ int woff[9];

  // runtime mask-dtype detection: first element is always valid (len >= 256)
  const uint32_t w0 = ((const uint32_t*)mask)[0];
  bool valid;
  if (w0 == 1u) {                       // int32 0/1
    valid = ((const int*)mask)[b * LEN + l] != 0;
  } else if (w0 == 0x3F800000u) {       // float32 0.0/1.0
    valid = ((const float*)mask)[b * LEN + l] != 0.0f;
  } else {                              // 1-byte bool
    valid = ((const unsigned char*)mask)[b * LEN + l] != 0;
  }
  const bool inv = !valid;

  uint32_t o0, o1;
  threefry2x32_k042(0u, (uint32_t)(b * LEN + l), o0, o1);
  const uint32_t bits = o0 ^ o1;
  const uint32_t ui = (bits >> 9) | 0x3F800000u;  // monotone in uniform value

  // order-preserving compaction of invalid slots
  const unsigned long long bal = __ballot(inv);
  const int lower = __popcll(bal & ((1ull << lane) - 1ull));
  if (lane == 0) wsum[wave] = __popcll(bal);
  __syncthreads();
  if (l == 0) {
    int acc = 0;
    for (int w = 0; w < 8; ++w) { woff[w] = acc; acc += wsum[w]; }
    woff[8] = acc;
  }
  __syncthreads();
  const int n_inv = woff[8];
  const int inv_before = woff[wave] + lower;  // # invalid with index < l
  if (inv) {
    inv_key[inv_before] = ui;
    inv_idx[inv_before] = l;
  }
  __syncthreads();

  int pos;
  if (inv) {
    int rank = 0;
    for (int j = 0; j < n_inv; ++j) {
      const uint32_t kj = inv_key[j];
      rank += (kj > ui || (kj == ui && inv_idx[j] < l)) ? 1 : 0;
    }
    pos = rank;
  } else {
    pos = n_inv + (l - inv_before);  // valid slots keep original order
  }
  src[b * LEN + pos] = l;
  dst[b * LEN + l] = pos;            // inverse permutation

  const int nv = LEN - n_inv;
  const int ml = nv < 1 ? 1 : nv;
  if (l == 0) ml_arr[b] = ml;
  mask_out[b * LEN + l] = (l >= n_inv && l < ml) ? 1.0f : 0.0f;
}

// ---------------- Kernel 2: uu + fused x/v gather (direction B) ----------
// out[b,c,i,j] = in[b,c,src[i],src[j]]. Block owns 32 consecutive OUTPUT
// rows -> writes are 100% dense sequential (64KB/block). Row reads go to
// src[i]: ~75% contiguous (valid-prefix shift), ~25% scattered 2KB rows,
// all issued upfront (deep MLP). Column gather in wave-private LDS row;
// no barriers. Linear block mapping (R6 showed XCD grouping hurts).
__global__ __launch_bounds__(256) void uu_perm(const float* __restrict__ in,
                                               float* __restrict__ out,
                                               const float* __restrict__ xin,
                                               const float* __restrict__ vin,
                                               float* __restrict__ xout,
                                               float* __restrict__ vout,
                                               const int* __restrict__ src,
                                               const int* __restrict__ ml_arr) {
  __shared__ float s_row[4][LEN];
  const int tid = threadIdx.x;
  const int wave = tid >> 6, lane = tid & 63;
  const int b = blockIdx.x >> 6;                 // 64 blocks per batch sample
  const int k = blockIdx.x & 63;
  const int orow0 = blockIdx.x * 32 + wave * 8;  // global OUTPUT row id
  const int i0 = orow0 & (LEN - 1);              // output row within plane
  const long plane = (long)(orow0 & ~(LEN - 1)) * LEN;
  const int* srcb_full = src + b * LEN;

  // source rows for my 8 output rows
  int rs[8];
#pragma unroll
  for (int r = 0; r < 8; ++r) rs[r] = srcb_full[i0 + r];

  // ---- issue all 16 row loads upfront (deep MLP) ----
  f4 a0[8], a1[8];
#pragma unroll
  for (int r = 0; r < 8; ++r) {
    const float* ip = in + plane + (long)rs[r] * LEN + lane * 8;
    a0[r] = *(const f4*)(ip);
    a1[r] = *(const f4*)(ip + 4);
  }

  // column gather sources (same for all rows)
  int c[8];
#pragma unroll
  for (int kk = 0; kk < 8; ++kk) c[kk] = srcb_full[lane * 8 + kk];

  float* myrow = &s_row[wave][0];
  float* op0 = out + plane + (long)i0 * LEN + lane * 8;

#pragma unroll
  for (int r = 0; r < 8; ++r) {
    *(f4*)(myrow + lane * 8) = a0[r];
    *(f4*)(myrow + lane * 8 + 4) = a1[r];
    f4 q0, q1;
    q0.x = myrow[c[0]]; q0.y = myrow[c[1]]; q0.z = myrow[c[2]]; q0.w = myrow[c[3]];
    q1.x = myrow[c[4]]; q1.y = myrow[c[5]]; q1.z = myrow[c[6]]; q1.w = myrow[c[7]];
    f4* op = (f4*)(op0 + (long)r * LEN);
    op[0] = q0;
    op[1] = q1;
  }

  // ---- fused x/v gather + trim for this (b, k); sequential writes ----
  const int ml = ml_arr[b];
  {
    const float* xrow = xin + (long)((b << 6) + k) * LEN;
    float* orow = xout + (long)((b << 6) + k) * LEN;
    for (int p = tid; p < LEN; p += 256) {
      orow[p] = (p < ml) ? xrow[srcb_full[p]] : 0.0f;
    }
  }
  if (k < NCV) {
    const float* vrow = vin + (long)((b << 2) + k) * LEN;
    float* orow = vout + (long)((b << 2) + k) * LEN;
    for (int p = tid; p < LEN; p += 256) {
      orow[p] = (p < ml) ? vrow[srcb_full[p]] : 0.0f;
    }
  }
}

extern "C" void kernel_launch(void* const* d_in, const int* in_sizes, int n_in,
                              void* d_out, int out_size, void* d_ws, size_t ws_size,
                              hipStream_t stream) {
  const float* x  = (const float*)d_in[0];   // (64,64,512)
  const float* v  = (const float*)d_in[1];   // (64,4,512)
  const float* uu = (const float*)d_in[2];   // (64,4,512,512)
  const void*  mask = d_in[3];               // (64,1,512)

  float* out   = (float*)d_out;
  float* out_x = out;                        // 2,097,152
  float* out_v = out + 2097152;              // 131,072
  float* out_m = out + 2228224;              // 32,768
  float* out_u = out + 2260992;              // 67,108,864

  int* src = (int*)d_ws;                     // 64*512 ints
  int* dst = src + NB * LEN;                 // 64*512 ints
  int* ml  = dst + NB * LEN;                 // 64 ints

  build_perm<<<NB, LEN, 0, stream>>>(mask, src, dst, ml, out_m);

  uu_perm<<<(NB * NCU * LEN) / 32, 256, 0, stream>>>(
      uu, out_u, x, v, out_x, out_v, src, ml);
}

// Round 8
// 132.665 us; speedup vs baseline: 1.1213x; 1.0179x over previous
//
#include <hip/hip_runtime.h>
#include <stdint.h>

#define LEN 512
#define NB 64
#define NCX 64
#define NCV 4
#define NCU 4

typedef float f4 __attribute__((ext_vector_type(4)));

// ---------------- Threefry-2x32, 20 rounds, key = (0, 42) ----------------
__device__ __forceinline__ uint32_t rotl32(uint32_t v, int r) {
  return (v << r) | (v >> (32 - r));
}

__device__ __forceinline__ void threefry2x32_k042(uint32_t c0, uint32_t c1,
                                                  uint32_t& o0, uint32_t& o1) {
  const uint32_t ks0 = 0u, ks1 = 42u;
  const uint32_t ks2 = 0u ^ 42u ^ 0x1BD11BDAu;
  uint32_t x0 = c0 + ks0;
  uint32_t x1 = c1 + ks1;
#define TF_ROUND(R) { x0 += x1; x1 = rotl32(x1, R); x1 ^= x0; }
  TF_ROUND(13) TF_ROUND(15) TF_ROUND(26) TF_ROUND(6)
  x0 += ks1; x1 += ks2 + 1u;
  TF_ROUND(17) TF_ROUND(29) TF_ROUND(16) TF_ROUND(24)
  x0 += ks2; x1 += ks0 + 2u;
  TF_ROUND(13) TF_ROUND(15) TF_ROUND(26) TF_ROUND(6)
  x0 += ks0; x1 += ks1 + 3u;
  TF_ROUND(17) TF_ROUND(29) TF_ROUND(16) TF_ROUND(24)
  x0 += ks1; x1 += ks2 + 4u;
  TF_ROUND(13) TF_ROUND(15) TF_ROUND(26) TF_ROUND(6)
  x0 += ks2; x1 += ks0 + 5u;
#undef TF_ROUND
  o0 = x0; o1 = x1;
}

// ---------------- Kernel 1: permutation (fwd + inverse), ml, mask_p -------
// perm semantics (matches jnp.argsort(-rand) stable ascending):
//   positions [0, n_inv): invalid slots ordered by rand DESC, ties idx ASC
//   positions [n_inv, L): valid slots in original index order
__global__ __launch_bounds__(LEN) void build_perm(const void* __restrict__ mask,
                                                  int* __restrict__ src,
                                                  int* __restrict__ dst,
                                                  int* __restrict__ ml_arr,
                                                  float* __restrict__ mask_out) {
  const int b = blockIdx.x;
  const int l = threadIdx.x;
  const int wave = l >> 6, lane = l & 63;
  __shared__ uint32_t inv_key[LEN];
  __shared__ int inv_idx[LEN];
  __shared__ int wsum[8];
  __shared__ int woff[9];

  // runtime mask-dtype detection: first element is always valid (len >= 256)
  const uint32_t w0 = ((const uint32_t*)mask)[0];
  bool valid;
  if (w0 == 1u) {                       // int32 0/1
    valid = ((const int*)mask)[b * LEN + l] != 0;
  } else if (w0 == 0x3F800000u) {       // float32 0.0/1.0
    valid = ((const float*)mask)[b * LEN + l] != 0.0f;
  } else {                              // 1-byte bool
    valid = ((const unsigned char*)mask)[b * LEN + l] != 0;
  }
  const bool inv = !valid;

  uint32_t o0, o1;
  threefry2x32_k042(0u, (uint32_t)(b * LEN + l), o0, o1);
  const uint32_t bits = o0 ^ o1;
  const uint32_t ui = (bits >> 9) | 0x3F800000u;  // monotone in uniform value

  // order-preserving compaction of invalid slots
  const unsigned long long bal = __ballot(inv);
  const int lower = __popcll(bal & ((1ull << lane) - 1ull));
  if (lane == 0) wsum[wave] = __popcll(bal);
  __syncthreads();
  if (l == 0) {
    int acc = 0;
    for (int w = 0; w < 8; ++w) { woff[w] = acc; acc += wsum[w]; }
    woff[8] = acc;
  }
  __syncthreads();
  const int n_inv = woff[8];
  const int inv_before = woff[wave] + lower;  // # invalid with index < l
  if (inv) {
    inv_key[inv_before] = ui;
    inv_idx[inv_before] = l;
  }
  __syncthreads();

  int pos;
  if (inv) {
    int rank = 0;
    for (int j = 0; j < n_inv; ++j) {
      const uint32_t kj = inv_key[j];
      rank += (kj > ui || (kj == ui && inv_idx[j] < l)) ? 1 : 0;
    }
    pos = rank;
  } else {
    pos = n_inv + (l - inv_before);  // valid slots keep original order
  }
  src[b * LEN + pos] = l;
  dst[b * LEN + l] = pos;            // inverse permutation

  const int nv = LEN - n_inv;
  const int ml = nv < 1 ? 1 : nv;
  if (l == 0) ml_arr[b] = ml;
  mask_out[b * LEN + l] = (l >= n_inv && l < ml) ? 1.0f : 0.0f;
}

// ---------------- Kernel 2: uu + fused x/v gather (direction B, dense) ----
// out[b,c,i,j] = in[b,c,src[i],src[j]]. Block owns 32 consecutive OUTPUT
// rows -> writes 100% dense sequential. Reads: ~75% sequential (valid-prefix
// shift), ~25% scattered 2KB rows, issued upfront.
// DENSE per-instruction lane mapping: each 2KB row = two 1KB segments,
// lane offset = lane*16B within a segment, so every global load / LDS write /
// global store instruction covers one contiguous 1KB block (R7's lane*32B
// stride was 50% dense -> 2x memory requests per byte).
__global__ __launch_bounds__(256) void uu_perm(const float* __restrict__ in,
                                               float* __restrict__ out,
                                               const float* __restrict__ xin,
                                               const float* __restrict__ vin,
                                               float* __restrict__ xout,
                                               float* __restrict__ vout,
                                               const int* __restrict__ src,
                                               const int* __restrict__ ml_arr) {
  __shared__ float s_row[4][LEN];
  const int tid = threadIdx.x;
  const int wave = tid >> 6, lane = tid & 63;
  const int b = blockIdx.x >> 6;                 // 64 blocks per batch sample
  const int k = blockIdx.x & 63;
  const int orow0 = blockIdx.x * 32 + wave * 8;  // global OUTPUT row id
  const int i0 = orow0 & (LEN - 1);              // output row within plane
  const long plane = (long)(orow0 & ~(LEN - 1)) * LEN;
  const int* srcb_full = src + b * LEN;

  // source rows for my 8 output rows
  int rs[8];
#pragma unroll
  for (int r = 0; r < 8; ++r) rs[r] = srcb_full[i0 + r];

  // ---- issue all 16 row loads upfront; each instr covers a dense 1KB ----
  f4 a0[8], a1[8];
#pragma unroll
  for (int r = 0; r < 8; ++r) {
    const float* ip = in + plane + (long)rs[r] * LEN + lane * 4;
    a0[r] = *(const f4*)(ip);          // bytes [lane*16, lane*16+16) of seg0
    a1[r] = *(const f4*)(ip + 256);    // same within seg1
  }

  // column gather sources: seg0 -> srcb[lane*4+k], seg1 -> srcb[256+lane*4+k]
  int c0[4], c1[4];
#pragma unroll
  for (int kk = 0; kk < 4; ++kk) {
    c0[kk] = srcb_full[lane * 4 + kk];
    c1[kk] = srcb_full[256 + lane * 4 + kk];
  }

  float* myrow = &s_row[wave][0];
  float* op0 = out + plane + (long)i0 * LEN + lane * 4;

#pragma unroll
  for (int r = 0; r < 8; ++r) {
    *(f4*)(myrow + lane * 4) = a0[r];          // dense 1KB LDS write
    *(f4*)(myrow + 256 + lane * 4) = a1[r];
    f4 q0, q1;
    q0.x = myrow[c0[0]]; q0.y = myrow[c0[1]]; q0.z = myrow[c0[2]]; q0.w = myrow[c0[3]];
    q1.x = myrow[c1[0]]; q1.y = myrow[c1[1]]; q1.z = myrow[c1[2]]; q1.w = myrow[c1[3]];
    f4* op = (f4*)(op0 + (long)r * LEN);
    op[0] = q0;                                 // dense 1KB store (seg0)
    *(f4*)((float*)op + 256) = q1;              // dense 1KB store (seg1)
  }

  // ---- fused x/v gather + trim for this (b, k); dense writes ----
  const int ml = ml_arr[b];
  {
    const float* xrow = xin + (long)((b << 6) + k) * LEN;
    float* orow = xout + (long)((b << 6) + k) * LEN;
    for (int p = tid; p < LEN; p += 256) {
      orow[p] = (p < ml) ? xrow[srcb_full[p]] : 0.0f;
    }
  }
  if (k < NCV) {
    const float* vrow = vin + (long)((b << 2) + k) * LEN;
    float* orow = vout + (long)((b << 2) + k) * LEN;
    for (int p = tid; p < LEN; p += 256) {
      orow[p] = (p < ml) ? vrow[srcb_full[p]] : 0.0f;
    }
  }
}

extern "C" void kernel_launch(void* const* d_in, const int* in_sizes, int n_in,
                              void* d_out, int out_size, void* d_ws, size_t ws_size,
                              hipStream_t stream) {
  const float* x  = (const float*)d_in[0];   // (64,64,512)
  const float* v  = (const float*)d_in[1];   // (64,4,512)
  const float* uu = (const float*)d_in[2];   // (64,4,512,512)
  const void*  mask = d_in[3];               // (64,1,512)

  float* out   = (float*)d_out;
  float* out_x = out;                        // 2,097,152
  float* out_v = out + 2097152;              // 131,072
  float* out_m = out + 2228224;              // 32,768
  float* out_u = out + 2260992;              // 67,108,864

  int* src = (int*)d_ws;                     // 64*512 ints
  int* dst = src + NB * LEN;                 // 64*512 ints
  int* ml  = dst + NB * LEN;                 // 64 ints

  build_perm<<<NB, LEN, 0, stream>>>(mask, src, dst, ml, out_m);

  uu_perm<<<(NB * NCU * LEN) / 32, 256, 0, stream>>>(
      uu, out_u, x, v, out_x, out_v, src, ml);
}

// Round 9
// 115.810 us; speedup vs baseline: 1.2845x; 1.1455x over previous
//
#include <hip/hip_runtime.h>
#include <stdint.h>

#define LEN 512
#define NB 64
#define NCX 64
#define NCV 4
#define NCU 4

typedef float f4 __attribute__((ext_vector_type(4)));

// ---------------- Threefry-2x32, 20 rounds, key = (0, 42) ----------------
__device__ __forceinline__ uint32_t rotl32(uint32_t v, int r) {
  return (v << r) | (v >> (32 - r));
}

__device__ __forceinline__ void threefry2x32_k042(uint32_t c0, uint32_t c1,
                                                  uint32_t& o0, uint32_t& o1) {
  const uint32_t ks0 = 0u, ks1 = 42u;
  const uint32_t ks2 = 0u ^ 42u ^ 0x1BD11BDAu;
  uint32_t x0 = c0 + ks0;
  uint32_t x1 = c1 + ks1;
#define TF_ROUND(R) { x0 += x1; x1 = rotl32(x1, R); x1 ^= x0; }
  TF_ROUND(13) TF_ROUND(15) TF_ROUND(26) TF_ROUND(6)
  x0 += ks1; x1 += ks2 + 1u;
  TF_ROUND(17) TF_ROUND(29) TF_ROUND(16) TF_ROUND(24)
  x0 += ks2; x1 += ks0 + 2u;
  TF_ROUND(13) TF_ROUND(15) TF_ROUND(26) TF_ROUND(6)
  x0 += ks0; x1 += ks1 + 3u;
  TF_ROUND(17) TF_ROUND(29) TF_ROUND(16) TF_ROUND(24)
  x0 += ks1; x1 += ks2 + 4u;
  TF_ROUND(13) TF_ROUND(15) TF_ROUND(26) TF_ROUND(6)
  x0 += ks2; x1 += ks0 + 5u;
#undef TF_ROUND
  o0 = x0; o1 = x1;
}

// ---------------- Kernel 1: permutation (fwd + inverse), ml, mask_p -------
// perm semantics (matches jnp.argsort(-rand) stable ascending):
//   positions [0, n_inv): invalid slots ordered by rand DESC, ties idx ASC
//   positions [n_inv, L): valid slots in original index order
// Rank via packed 32-bit keys: (23-bit mantissa << 9) | (511 - idx), so
// "kj > me || (kj == me && idxj < l)" == single unsigned compare. Scanned
// with uint4 LDS broadcast loads (8 cmp per latency window), killing the
// previous dependent-load serial chain (~130 cyc/iter exposed).
__global__ __launch_bounds__(LEN) void build_perm(const void* __restrict__ mask,
                                                  int* __restrict__ src,
                                                  int* __restrict__ dst,
                                                  int* __restrict__ ml_arr,
                                                  float* __restrict__ mask_out) {
  const int b = blockIdx.x;
  const int l = threadIdx.x;
  const int wave = l >> 6, lane = l & 63;
  __shared__ alignas(16) uint32_t s_pack[LEN];
  __shared__ int wsum[8];
  __shared__ int woff[9];

  // runtime mask-dtype detection: first element is always valid (len >= 256)
  const uint32_t w0 = ((const uint32_t*)mask)[0];
  bool valid;
  if (w0 == 1u) {                       // int32 0/1
    valid = ((const int*)mask)[b * LEN + l] != 0;
  } else if (w0 == 0x3F800000u) {       // float32 0.0/1.0
    valid = ((const float*)mask)[b * LEN + l] != 0.0f;
  } else {                              // 1-byte bool
    valid = ((const unsigned char*)mask)[b * LEN + l] != 0;
  }
  const bool inv = !valid;

  uint32_t o0, o1;
  threefry2x32_k042(0u, (uint32_t)(b * LEN + l), o0, o1);
  const uint32_t bits = o0 ^ o1;
  const uint32_t ui = (bits >> 9) | 0x3F800000u;  // monotone in uniform value
  const uint32_t me = ((ui & 0x7FFFFFu) << 9) | (uint32_t)(511 - l);

  // order-preserving compaction of invalid slots
  const unsigned long long bal = __ballot(inv);
  const int lower = __popcll(bal & ((1ull << lane) - 1ull));
  if (lane == 0) wsum[wave] = __popcll(bal);
  __syncthreads();
  if (l == 0) {
    int acc = 0;
    for (int w = 0; w < 8; ++w) { woff[w] = acc; acc += wsum[w]; }
    woff[8] = acc;
  }
  __syncthreads();
  const int n_inv = woff[8];
  const int inv_before = woff[wave] + lower;  // # invalid with index < l
  if (inv) {
    s_pack[inv_before] = me;
  }
  __syncthreads();

  int pos;
  if (inv) {
    int rank = 0;
    int j = 0;
    for (; j + 8 <= n_inv; j += 8) {
      const uint4 p0 = *(const uint4*)&s_pack[j];
      const uint4 p1 = *(const uint4*)&s_pack[j + 4];
      rank += (int)(p0.x > me) + (int)(p0.y > me) + (int)(p0.z > me) +
              (int)(p0.w > me) + (int)(p1.x > me) + (int)(p1.y > me) +
              (int)(p1.z > me) + (int)(p1.w > me);
    }
    for (; j < n_inv; ++j) rank += (int)(s_pack[j] > me);
    pos = rank;
  } else {
    pos = n_inv + (l - inv_before);  // valid slots keep original order
  }
  src[b * LEN + pos] = l;
  dst[b * LEN + l] = pos;            // inverse permutation

  const int nv = LEN - n_inv;
  const int ml = nv < 1 ? 1 : nv;
  if (l == 0) ml_arr[b] = ml;
  mask_out[b * LEN + l] = (l >= n_inv && l < ml) ? 1.0f : 0.0f;
}

// ---------------- Kernel 2: uu + fused x/v gather (direction B, dense) ----
// out[b,c,i,j] = in[b,c,src[i],src[j]]. Block owns 32 consecutive OUTPUT
// rows -> writes 100% dense sequential. Reads: ~75% sequential (valid-prefix
// shift), ~25% scattered 2KB rows, issued upfront.
// DENSE per-instruction lane mapping: each 2KB row = two 1KB segments,
// lane offset = lane*16B within a segment, so every global load / LDS write /
// global store instruction covers one contiguous 1KB block.
__global__ __launch_bounds__(256) void uu_perm(const float* __restrict__ in,
                                               float* __restrict__ out,
                                               const float* __restrict__ xin,
                                               const float* __restrict__ vin,
                                               float* __restrict__ xout,
                                               float* __restrict__ vout,
                                               const int* __restrict__ src,
                                               const int* __restrict__ ml_arr) {
  __shared__ float s_row[4][LEN];
  const int tid = threadIdx.x;
  const int wave = tid >> 6, lane = tid & 63;
  const int b = blockIdx.x >> 6;                 // 64 blocks per batch sample
  const int k = blockIdx.x & 63;
  const int orow0 = blockIdx.x * 32 + wave * 8;  // global OUTPUT row id
  const int i0 = orow0 & (LEN - 1);              // output row within plane
  const long plane = (long)(orow0 & ~(LEN - 1)) * LEN;
  const int* srcb_full = src + b * LEN;

  // source rows for my 8 output rows
  int rs[8];
#pragma unroll
  for (int r = 0; r < 8; ++r) rs[r] = srcb_full[i0 + r];

  // ---- issue all 16 row loads upfront; each instr covers a dense 1KB ----
  f4 a0[8], a1[8];
#pragma unroll
  for (int r = 0; r < 8; ++r) {
    const float* ip = in + plane + (long)rs[r] * LEN + lane * 4;
    a0[r] = *(const f4*)(ip);          // bytes [lane*16, lane*16+16) of seg0
    a1[r] = *(const f4*)(ip + 256);    // same within seg1
  }

  // column gather sources: seg0 -> srcb[lane*4+k], seg1 -> srcb[256+lane*4+k]
  int c0[4], c1[4];
#pragma unroll
  for (int kk = 0; kk < 4; ++kk) {
    c0[kk] = srcb_full[lane * 4 + kk];
    c1[kk] = srcb_full[256 + lane * 4 + kk];
  }

  float* myrow = &s_row[wave][0];
  float* op0 = out + plane + (long)i0 * LEN + lane * 4;

#pragma unroll
  for (int r = 0; r < 8; ++r) {
    *(f4*)(myrow + lane * 4) = a0[r];          // dense 1KB LDS write
    *(f4*)(myrow + 256 + lane * 4) = a1[r];
    f4 q0, q1;
    q0.x = myrow[c0[0]]; q0.y = myrow[c0[1]]; q0.z = myrow[c0[2]]; q0.w = myrow[c0[3]];
    q1.x = myrow[c1[0]]; q1.y = myrow[c1[1]]; q1.z = myrow[c1[2]]; q1.w = myrow[c1[3]];
    f4* op = (f4*)(op0 + (long)r * LEN);
    op[0] = q0;                                 // dense 1KB store (seg0)
    *(f4*)((float*)op + 256) = q1;              // dense 1KB store (seg1)
  }

  // ---- fused x/v gather + trim for this (b, k); dense writes ----
  const int ml = ml_arr[b];
  {
    const float* xrow = xin + (long)((b << 6) + k) * LEN;
    float* orow = xout + (long)((b << 6) + k) * LEN;
    for (int p = tid; p < LEN; p += 256) {
      orow[p] = (p < ml) ? xrow[srcb_full[p]] : 0.0f;
    }
  }
  if (k < NCV) {
    const float* vrow = vin + (long)((b << 2) + k) * LEN;
    float* orow = vout + (long)((b << 2) + k) * LEN;
    for (int p = tid; p < LEN; p += 256) {
      orow[p] = (p < ml) ? vrow[srcb_full[p]] : 0.0f;
    }
  }
}

extern "C" void kernel_launch(void* const* d_in, const int* in_sizes, int n_in,
                              void* d_out, int out_size, void* d_ws, size_t ws_size,
                              hipStream_t stream) {
  const float* x  = (const float*)d_in[0];   // (64,64,512)
  const float* v  = (const float*)d_in[1];   // (64,4,512)
  const float* uu = (const float*)d_in[2];   // (64,4,512,512)
  const void*  mask = d_in[3];               // (64,1,512)

  float* out   = (float*)d_out;
  float* out_x = out;                        // 2,097,152
  float* out_v = out + 2097152;              // 131,072
  float* out_m = out + 2228224;              // 32,768
  float* out_u = out + 2260992;              // 67,108,864

  int* src = (int*)d_ws;                     // 64*512 ints
  int* dst = src + NB * LEN;                 // 64*512 ints
  int* ml  = dst + NB * LEN;                 // 64 ints

  build_perm<<<NB, LEN, 0, stream>>>(mask, src, dst, ml, out_m);

  uu_perm<<<(NB * NCU * LEN) / 32, 256, 0, stream>>>(
      uu, out_u, x, v, out_x, out_v, src, ml);
}